// Round 5
// baseline (113.526 us; speedup 1.0000x reference)
//
#include <hip/hip_runtime.h>

// Problem dims (fixed by reference)
#define BB 4
#define LL 1024
#define DD 64
#define UU 32
#define TI 8     // query rows per block
#define NT 512   // threads per block (8 waves)

// ---------------------------------------------------------------------------
// K1: Ekt[b,u4,j] = float4 of exp(2*(inp@Wx)) for u=4*u4..4*u4+3 (transposed:
// lane-consecutive j -> coalesced float4 loads in attn phase A).
// tanh(q+k+bh) = 1 - 2/(1 + Eq*Ek); Eq is computed per-block inside attn.
// ---------------------------------------------------------------------------
__global__ __launch_bounds__(256) void precompute_kernel(
    const float* __restrict__ inp, const float* __restrict__ Wx,
    float* __restrict__ Ekt)
{
    __shared__ float s_in[8][DD];       // 2 KB
    __shared__ float s_wx[DD][UU];      // 8 KB
    __shared__ float s_ek[8][36];       // padded: conflict-free b128 reads
    int t = threadIdx.x;
    int row0 = blockIdx.x * 8;
    if (t < 128)
        ((float4*)s_in)[t] = ((const float4*)(inp + (size_t)row0 * DD))[t];
#pragma unroll
    for (int p = 0; p < 2; ++p)
        ((float4*)s_wx)[p * 256 + t] = ((const float4*)Wx)[p * 256 + t];
    __syncthreads();
    int r = t >> 5;
    int u = t & 31;
    float k = 0.f;
#pragma unroll
    for (int d = 0; d < DD; ++d)
        k = fmaf(s_in[r][d], s_wx[d][u], k);
    s_ek[r][u] = __expf(2.f * k);
    __syncthreads();
    // transposed write: Ekt[(b*8 + u4)*LL + l] (float4 units)
    if (t < 64) {
        int u4 = t >> 3, r2 = t & 7;
        float4 v = *(const float4*)(&s_ek[r2][u4 * 4]);
        size_t gr = row0 + r2;
        size_t bb_ = gr >> 10, l = gr & 1023;
        ((float4*)Ekt)[(bb_ * 8 + u4) * LL + l] = v;
    }
}

// ---------------------------------------------------------------------------
// K2: stage(inp rows + Wt) -> Eq tile in LDS -> scores -> softmax -> v.
// TI=8 rows/block, 512 threads, grid = B*L/TI = 512 blocks (2/CU).
// Phase A quad-rcp: sum_u wa_u/p_u over a u-quad with one v_rcp.
// KEY CHANGE vs R4: Eq read from LDS (ds_read_b128 broadcast) instead of
// global scalar loads -> no per-iteration s_load/lgkmcnt serialization.
// ---------------------------------------------------------------------------
union ShMem {
    struct { float wt[DD][UU]; float in[TI][DD]; } pre;   // 8 KB + 2 KB (staging)
    struct { float a0[LL][4]; float a1[LL][4]; } a;       // 32 KB (softmax->B)
    float4 v[8][TI][16];                                   // 16 KB (epilogue)
};

__global__ __launch_bounds__(NT, 4) void attn_kernel(
    const float* __restrict__ Ekt, const float* __restrict__ inp,
    const float* __restrict__ Wt, const float* __restrict__ Wa,
    const float* __restrict__ bh, float* __restrict__ out)
{
    __shared__ ShMem sh;
    __shared__ float s_eq[TI][UU];      // 1 KB, live through phase A
    __shared__ float s_red[2][8][TI];   // [stage][wave][row]

    int t  = threadIdx.x;
    int w  = t >> 6;                    // wave 0..7
    int b  = blockIdx.x >> 7;
    int i0 = (blockIdx.x & 127) * TI;

    // ---------------- Phase 0: stage inp rows + Wt, compute Eq tile ---------
    if (t < 128)
        ((float4*)sh.pre.in)[t] =
            ((const float4*)(inp + (size_t)(b * LL + i0) * DD))[t];
    ((float4*)sh.pre.wt)[t] = ((const float4*)Wt)[t];   // 512 float4 = all of Wt
    __syncthreads();                                             // B0
    if (t < TI * UU) {
        int i = t >> 5, u = t & 31;
        float q = 0.f;
#pragma unroll
        for (int d = 0; d < DD; ++d)
            q = fmaf(sh.pre.in[i][d], sh.pre.wt[d][u], q);
        s_eq[i][u] = __expf(2.f * (q + bh[u]));
    }
    __syncthreads();                                             // B0b

    // ---------------- Phase A: scores (u4-outer, double-buffered Ekt) -------
    const float4* ektb = (const float4*)Ekt + (size_t)b * 8 * LL;
    float acc[TI][2];
#pragma unroll
    for (int i = 0; i < TI; ++i) { acc[i][0] = 0.f; acc[i][1] = 0.f; }

    float4 cur0 = ektb[t], cur1 = ektb[NT + t];     // coalesced

#pragma unroll
    for (int u4 = 0; u4 < 8; ++u4) {
        float4 nxt0, nxt1;
        if (u4 < 7) {
            nxt0 = ektb[(u4 + 1) * LL + t];
            nxt1 = ektb[(u4 + 1) * LL + NT + t];
        }
        float4 wav = *(const float4*)(Wa + u4 * 4);  // uniform -> hoistable s_load
        float wa0 = wav.x, wa1 = wav.y, wa2 = wav.z, wa3 = wav.w;
#pragma unroll
        for (int i = 0; i < TI; ++i) {
            float4 eqv = *(const float4*)(&s_eq[i][u4 * 4]);   // b128 broadcast
            float eq0 = eqv.x, eq1 = eqv.y, eq2 = eqv.z, eq3 = eqv.w;
#pragma unroll
            for (int jj = 0; jj < 2; ++jj) {
                float4 ek = jj ? cur1 : cur0;
                float p  = fmaf(eq0, ek.x, 1.f);
                float q  = fmaf(eq1, ek.y, 1.f);
                float r  = fmaf(eq2, ek.z, 1.f);
                float s  = fmaf(eq3, ek.w, 1.f);
                float n01 = fmaf(wa0, q, wa1 * p);
                float n23 = fmaf(wa2, s, wa3 * r);
                float pq = p * q, rs = r * s;
                float num = fmaf(n01, rs, n23 * pq);
                float den = pq * rs;                 // <= ~4e22, safe in fp32
                acc[i][jj] = fmaf(num, __builtin_amdgcn_rcpf(den), acc[i][jj]);
            }
        }
        if (u4 < 7) { cur0 = nxt0; cur1 = nxt1; }
    }

    float ev[TI][2];
#pragma unroll
    for (int i = 0; i < TI; ++i) {
        ev[i][0] = -2.f * acc[i][0];
        ev[i][1] = -2.f * acc[i][1];
    }

    // ---------------- Softmax: batched wave reductions, 2 barriers ----------
    float wred[TI];
#pragma unroll
    for (int i = 0; i < TI; ++i) {
        float v = fmaxf(ev[i][0], ev[i][1]);
#pragma unroll
        for (int m = 32; m >= 1; m >>= 1) v = fmaxf(v, __shfl_xor(v, m, 64));
        wred[i] = v;
    }
    if ((t & 63) == 0) {
#pragma unroll
        for (int i = 0; i < TI; ++i) s_red[0][w][i] = wred[i];
    }
    __syncthreads();                                             // B1
    float m[TI];
#pragma unroll
    for (int i = 0; i < TI; ++i) {
        float v = s_red[0][0][i];
#pragma unroll
        for (int w2 = 1; w2 < 8; ++w2) v = fmaxf(v, s_red[0][w2][i]);
        m[i] = v;
    }

#pragma unroll
    for (int i = 0; i < TI; ++i) {
        ev[i][0] = __expf(ev[i][0] - m[i]);
        ev[i][1] = __expf(ev[i][1] - m[i]);
        float s = ev[i][0] + ev[i][1];
#pragma unroll
        for (int mm = 32; mm >= 1; mm >>= 1) s += __shfl_xor(s, mm, 64);
        wred[i] = s;
    }
    if ((t & 63) == 0) {
#pragma unroll
        for (int i = 0; i < TI; ++i) s_red[1][w][i] = wred[i];
    }
    __syncthreads();                                             // B2
    float rs[TI];
#pragma unroll
    for (int i = 0; i < TI; ++i) {
        float s = 0.f;
#pragma unroll
        for (int w2 = 0; w2 < 8; ++w2) s += s_red[1][w2][i];
        rs[i] = 1.0f / (s + 1e-8f);          // reference's +1e-8 denominator
    }

#pragma unroll
    for (int jj = 0; jj < 2; ++jj) {
        int j = jj * NT + t;
        float4 lo, hi;
        lo.x = ev[0][jj] * rs[0]; lo.y = ev[1][jj] * rs[1];
        lo.z = ev[2][jj] * rs[2]; lo.w = ev[3][jj] * rs[3];
        hi.x = ev[4][jj] * rs[4]; hi.y = ev[5][jj] * rs[5];
        hi.z = ev[6][jj] * rs[6]; hi.w = ev[7][jj] * rs[7];
        *(float4*)(&sh.a.a0[j][0]) = lo;
        *(float4*)(&sh.a.a1[j][0]) = hi;
    }
    __syncthreads();                                             // B3

    // ---------------- Phase B: v = a @ inputs (4-deep x prefetch) -----------
    int dq = t & 15;        // d-quad
    int g  = t >> 4;        // j-group 0..31
    const float4* inp4 = (const float4*)(inp + (size_t)b * LL * DD);
    float4 v[TI];
#pragma unroll
    for (int i = 0; i < TI; ++i) v[i] = (float4){0.f, 0.f, 0.f, 0.f};

    float4 xbuf[4];
#pragma unroll
    for (int p = 0; p < 4; ++p) xbuf[p] = inp4[(p * 32 + g) * 16 + dq];

#pragma unroll 2
    for (int jo = 0; jo < 8; ++jo) {
#pragma unroll
        for (int p = 0; p < 4; ++p) {
            int jj = jo * 4 + p;
            int j  = jj * 32 + g;
            float4 x = xbuf[p];
            if (jo < 7) xbuf[p] = inp4[((jj + 4) * 32 + g) * 16 + dq];
            float4 a0 = *(const float4*)(&sh.a.a0[j][0]);   // b128 broadcast
            float4 a1 = *(const float4*)(&sh.a.a1[j][0]);
            v[0].x = fmaf(a0.x, x.x, v[0].x); v[0].y = fmaf(a0.x, x.y, v[0].y);
            v[0].z = fmaf(a0.x, x.z, v[0].z); v[0].w = fmaf(a0.x, x.w, v[0].w);
            v[1].x = fmaf(a0.y, x.x, v[1].x); v[1].y = fmaf(a0.y, x.y, v[1].y);
            v[1].z = fmaf(a0.y, x.z, v[1].z); v[1].w = fmaf(a0.y, x.w, v[1].w);
            v[2].x = fmaf(a0.z, x.x, v[2].x); v[2].y = fmaf(a0.z, x.y, v[2].y);
            v[2].z = fmaf(a0.z, x.z, v[2].z); v[2].w = fmaf(a0.z, x.w, v[2].w);
            v[3].x = fmaf(a0.w, x.x, v[3].x); v[3].y = fmaf(a0.w, x.y, v[3].y);
            v[3].z = fmaf(a0.w, x.z, v[3].z); v[3].w = fmaf(a0.w, x.w, v[3].w);
            v[4].x = fmaf(a1.x, x.x, v[4].x); v[4].y = fmaf(a1.x, x.y, v[4].y);
            v[4].z = fmaf(a1.x, x.z, v[4].z); v[4].w = fmaf(a1.x, x.w, v[4].w);
            v[5].x = fmaf(a1.y, x.x, v[5].x); v[5].y = fmaf(a1.y, x.y, v[5].y);
            v[5].z = fmaf(a1.y, x.z, v[5].z); v[5].w = fmaf(a1.y, x.w, v[5].w);
            v[6].x = fmaf(a1.z, x.x, v[6].x); v[6].y = fmaf(a1.z, x.y, v[6].y);
            v[6].z = fmaf(a1.z, x.z, v[6].z); v[6].w = fmaf(a1.z, x.w, v[6].w);
            v[7].x = fmaf(a1.w, x.x, v[7].x); v[7].y = fmaf(a1.w, x.y, v[7].y);
            v[7].z = fmaf(a1.w, x.z, v[7].z); v[7].w = fmaf(a1.w, x.w, v[7].w);
        }
    }

    // reduce 4 j-groups within each wave (lanes differ in bits 4,5 of t)
#pragma unroll
    for (int i = 0; i < TI; ++i) {
        v[i].x += __shfl_xor(v[i].x, 16, 64); v[i].y += __shfl_xor(v[i].y, 16, 64);
        v[i].z += __shfl_xor(v[i].z, 16, 64); v[i].w += __shfl_xor(v[i].w, 16, 64);
        v[i].x += __shfl_xor(v[i].x, 32, 64); v[i].y += __shfl_xor(v[i].y, 32, 64);
        v[i].z += __shfl_xor(v[i].z, 32, 64); v[i].w += __shfl_xor(v[i].w, 32, 64);
    }
    __syncthreads();                     // B4: all a-reads done before union reuse
    if ((t & 63) < 16) {
#pragma unroll
        for (int i = 0; i < TI; ++i) sh.v[w][i][dq] = v[i];
    }
    __syncthreads();                                             // B5

    // final cross-wave reduce + coalesced store (512 output elements)
    int i = t >> 6;       // 0..7
    int d = t & 63;       // 0..63
    const float* svf = (const float*)sh.v;
    float r = 0.f;
#pragma unroll
    for (int w2 = 0; w2 < 8; ++w2) r += svf[w2 * (TI * 64) + i * 64 + d];
    out[((size_t)b * LL + (i0 + i)) * DD + d] = r;
}

// ---------------------------------------------------------------------------
extern "C" void kernel_launch(void* const* d_in, const int* in_sizes, int n_in,
                              void* d_out, int out_size, void* d_ws, size_t ws_size,
                              hipStream_t stream) {
    const float* inp = (const float*)d_in[0];
    const float* Wt  = (const float*)d_in[1];
    const float* Wx  = (const float*)d_in[2];
    const float* Wa  = (const float*)d_in[3];
    const float* bh  = (const float*)d_in[4];
    // d_in[5] = ba (cancels in softmax), d_in[6] = attention_width (dead code)
    float* out = (float*)d_out;

    float* Ekt = (float*)d_ws;                      // transposed Ek, 512 KB

    precompute_kernel<<<BB * LL / 8, 256, 0, stream>>>(inp, Wx, Ekt);
    attn_kernel<<<BB * LL / TI, NT, 0, stream>>>(Ekt, inp, Wt, Wa, bh, out);
}

// Round 6
// 103.967 us; speedup vs baseline: 1.0919x; 1.0919x over previous
//
#include <hip/hip_runtime.h>

// Problem dims (fixed by reference)
#define BB 4
#define LL 1024
#define DD 64
#define UU 32
#define TI 8     // query rows per block
#define NT 512   // threads per block (8 waves)
#define JH 512   // j's per half (j-split: 2 halves)

// ---------------------------------------------------------------------------
// K1: Ekt[b,u4,j] = float4 of exp(2*(inp@Wx)) for u=4*u4..4*u4+3 (transposed:
// lane-consecutive j -> coalesced float4 loads in attn phase A).
// tanh(q+k+bh) = 1 - 2/(1 + Eq*Ek); Eq is computed per-block inside attn.
// ---------------------------------------------------------------------------
__global__ __launch_bounds__(256) void precompute_kernel(
    const float* __restrict__ inp, const float* __restrict__ Wx,
    float* __restrict__ Ekt)
{
    __shared__ float s_in[8][DD];       // 2 KB
    __shared__ float s_wx[DD][UU];      // 8 KB
    __shared__ float s_ek[8][36];       // padded: conflict-free b128 reads
    int t = threadIdx.x;
    int row0 = blockIdx.x * 8;
    if (t < 128)
        ((float4*)s_in)[t] = ((const float4*)(inp + (size_t)row0 * DD))[t];
#pragma unroll
    for (int p = 0; p < 2; ++p)
        ((float4*)s_wx)[p * 256 + t] = ((const float4*)Wx)[p * 256 + t];
    __syncthreads();
    int r = t >> 5;
    int u = t & 31;
    float k = 0.f;
#pragma unroll
    for (int d = 0; d < DD; ++d)
        k = fmaf(s_in[r][d], s_wx[d][u], k);
    s_ek[r][u] = __expf(2.f * k);
    __syncthreads();
    // transposed write: Ekt[(b*8 + u4)*LL + l] (float4 units)
    if (t < 64) {
        int u4 = t >> 3, r2 = t & 7;
        float4 v = *(const float4*)(&s_ek[r2][u4 * 4]);
        size_t gr = row0 + r2;
        size_t bb_ = gr >> 10, l = gr & 1023;
        ((float4*)Ekt)[(bb_ * 8 + u4) * LL + l] = v;
    }
}

// ---------------------------------------------------------------------------
// K2: j-split partial attention. Block = (rowblk, jh): TI=8 rows x 512 j's.
// grid = 2 * B*L/TI = 1024 blocks (4/CU -> up to 32 waves/CU).
// Emits UNNORMALIZED partials: pm = local max, ps = local sum(ex),
// po = sum(ex * x). Combine kernel merges the two halves.
// No restrictive launch bound (R5's (NT,4) caused scratch spills: VGPR=64,
// WRITE_SIZE 57 MB).
// ---------------------------------------------------------------------------
union ShMem {
    struct { float wt[DD][UU]; float in[TI][DD]; } pre;   // 10 KB (staging)
    struct { float a[JH][TI]; } sm;                        // 16 KB (ex table)
    float4 v[8][TI][16];                                   // 16 KB (epilogue)
};

__global__ __launch_bounds__(NT) void attn_partial_kernel(
    const float* __restrict__ Ekt, const float* __restrict__ inp,
    const float* __restrict__ Wt, const float* __restrict__ Wa,
    const float* __restrict__ bh,
    float* __restrict__ po, float* __restrict__ pm, float* __restrict__ ps)
{
    __shared__ ShMem sh;
    __shared__ float s_eq[TI][UU];      // 1 KB, live through phase A
    __shared__ float s_red[2][8][TI];   // [stage][wave][row]

    int t      = threadIdx.x;
    int w      = t >> 6;                // wave 0..7
    int bid    = blockIdx.x;
    int rowblk = bid >> 1;              // 0..511
    int jh     = bid & 1;               // j-half
    int b      = rowblk >> 7;
    int i0     = (rowblk & 127) * TI;
    int j0     = jh * JH;

    // ---------------- Phase 0: stage inp rows + Wt, compute Eq tile ---------
    if (t < 128)
        ((float4*)sh.pre.in)[t] =
            ((const float4*)(inp + (size_t)(b * LL + i0) * DD))[t];
    ((float4*)sh.pre.wt)[t] = ((const float4*)Wt)[t];   // 512 float4 = all of Wt
    __syncthreads();                                             // B0
    if (t < TI * UU) {
        int i = t >> 5, u = t & 31;
        float q = 0.f;
#pragma unroll
        for (int d = 0; d < DD; ++d)
            q = fmaf(sh.pre.in[i][d], sh.pre.wt[d][u], q);
        s_eq[i][u] = __expf(2.f * (q + bh[u]));
    }
    __syncthreads();                                             // B0b

    // ---------------- Phase A: scores for j = j0 + t ------------------------
    const float4* ektb = (const float4*)Ekt + (size_t)b * 8 * LL;
    float acc[TI];
#pragma unroll
    for (int i = 0; i < TI; ++i) acc[i] = 0.f;

    float4 cur = ektb[j0 + t];          // coalesced

#pragma unroll
    for (int u4 = 0; u4 < 8; ++u4) {
        float4 nxt;
        if (u4 < 7) nxt = ektb[(u4 + 1) * LL + j0 + t];
        float4 wav = *(const float4*)(Wa + u4 * 4);  // uniform -> s_load
        float wa0 = wav.x, wa1 = wav.y, wa2 = wav.z, wa3 = wav.w;
#pragma unroll
        for (int i = 0; i < TI; ++i) {
            float4 eqv = *(const float4*)(&s_eq[i][u4 * 4]);   // b128 broadcast
            float p  = fmaf(eqv.x, cur.x, 1.f);
            float q  = fmaf(eqv.y, cur.y, 1.f);
            float r  = fmaf(eqv.z, cur.z, 1.f);
            float s  = fmaf(eqv.w, cur.w, 1.f);
            float n01 = fmaf(wa0, q, wa1 * p);
            float n23 = fmaf(wa2, s, wa3 * r);
            float pq = p * q, rs = r * s;
            float num = fmaf(n01, rs, n23 * pq);
            float den = pq * rs;                     // <= ~4e22, safe in fp32
            acc[i] = fmaf(num, __builtin_amdgcn_rcpf(den), acc[i]);
        }
        if (u4 < 7) cur = nxt;
    }

    float ev[TI];
#pragma unroll
    for (int i = 0; i < TI; ++i) ev[i] = -2.f * acc[i];

    // ---------------- Partial softmax: local max + local sum ----------------
    float wred[TI];
#pragma unroll
    for (int i = 0; i < TI; ++i) {
        float v = ev[i];
#pragma unroll
        for (int m = 32; m >= 1; m >>= 1) v = fmaxf(v, __shfl_xor(v, m, 64));
        wred[i] = v;
    }
    if ((t & 63) == 0) {
#pragma unroll
        for (int i = 0; i < TI; ++i) s_red[0][w][i] = wred[i];
    }
    __syncthreads();                                             // B1
    float m[TI];
#pragma unroll
    for (int i = 0; i < TI; ++i) {
        float v = s_red[0][0][i];
#pragma unroll
        for (int w2 = 1; w2 < 8; ++w2) v = fmaxf(v, s_red[0][w2][i]);
        m[i] = v;
    }

#pragma unroll
    for (int i = 0; i < TI; ++i) {
        ev[i] = __expf(ev[i] - m[i]);     // unnormalized ex
        float s = ev[i];
#pragma unroll
        for (int mm = 32; mm >= 1; mm >>= 1) s += __shfl_xor(s, mm, 64);
        wred[i] = s;
    }
    if ((t & 63) == 0) {
#pragma unroll
        for (int i = 0; i < TI; ++i) s_red[1][w][i] = wred[i];
    }
    __syncthreads();                                             // B2
    float sl[TI];
#pragma unroll
    for (int i = 0; i < TI; ++i) {
        float s = 0.f;
#pragma unroll
        for (int w2 = 0; w2 < 8; ++w2) s += s_red[1][w2][i];
        sl[i] = s;
    }
    if (t == 0) {
#pragma unroll
        for (int i = 0; i < TI; ++i) {
            pm[rowblk * 16 + jh * 8 + i] = m[i];
            ps[rowblk * 16 + jh * 8 + i] = sl[i];
        }
    }

    // ex table to LDS: s_a[jl][i]
    {
        float4 lo, hi;
        lo.x = ev[0]; lo.y = ev[1]; lo.z = ev[2]; lo.w = ev[3];
        hi.x = ev[4]; hi.y = ev[5]; hi.z = ev[6]; hi.w = ev[7];
        *(float4*)(&sh.sm.a[t][0]) = lo;
        *(float4*)(&sh.sm.a[t][4]) = hi;
    }
    __syncthreads();                                             // B3

    // ---------------- Phase B: po = ex @ x over this j-half -----------------
    int dq = t & 15;        // d-quad
    int g  = t >> 4;        // j-group 0..31
    const float4* inp4 = (const float4*)(inp + (size_t)b * LL * DD);
    float4 v[TI];
#pragma unroll
    for (int i = 0; i < TI; ++i) v[i] = (float4){0.f, 0.f, 0.f, 0.f};

#pragma unroll 4
    for (int jj = 0; jj < 16; ++jj) {
        int jl = jj * 32 + g;
        float4 x  = inp4[(size_t)(j0 + jl) * 16 + dq];
        float4 a0 = *(const float4*)(&sh.sm.a[jl][0]);   // b128 broadcast
        float4 a1 = *(const float4*)(&sh.sm.a[jl][4]);
        v[0].x = fmaf(a0.x, x.x, v[0].x); v[0].y = fmaf(a0.x, x.y, v[0].y);
        v[0].z = fmaf(a0.x, x.z, v[0].z); v[0].w = fmaf(a0.x, x.w, v[0].w);
        v[1].x = fmaf(a0.y, x.x, v[1].x); v[1].y = fmaf(a0.y, x.y, v[1].y);
        v[1].z = fmaf(a0.y, x.z, v[1].z); v[1].w = fmaf(a0.y, x.w, v[1].w);
        v[2].x = fmaf(a0.z, x.x, v[2].x); v[2].y = fmaf(a0.z, x.y, v[2].y);
        v[2].z = fmaf(a0.z, x.z, v[2].z); v[2].w = fmaf(a0.z, x.w, v[2].w);
        v[3].x = fmaf(a0.w, x.x, v[3].x); v[3].y = fmaf(a0.w, x.y, v[3].y);
        v[3].z = fmaf(a0.w, x.z, v[3].z); v[3].w = fmaf(a0.w, x.w, v[3].w);
        v[4].x = fmaf(a1.x, x.x, v[4].x); v[4].y = fmaf(a1.x, x.y, v[4].y);
        v[4].z = fmaf(a1.x, x.z, v[4].z); v[4].w = fmaf(a1.x, x.w, v[4].w);
        v[5].x = fmaf(a1.y, x.x, v[5].x); v[5].y = fmaf(a1.y, x.y, v[5].y);
        v[5].z = fmaf(a1.y, x.z, v[5].z); v[5].w = fmaf(a1.y, x.w, v[5].w);
        v[6].x = fmaf(a1.z, x.x, v[6].x); v[6].y = fmaf(a1.z, x.y, v[6].y);
        v[6].z = fmaf(a1.z, x.z, v[6].z); v[6].w = fmaf(a1.z, x.w, v[6].w);
        v[7].x = fmaf(a1.w, x.x, v[7].x); v[7].y = fmaf(a1.w, x.y, v[7].y);
        v[7].z = fmaf(a1.w, x.z, v[7].z); v[7].w = fmaf(a1.w, x.w, v[7].w);
    }

    // reduce 4 j-groups within each wave (lanes differ in bits 4,5 of t)
#pragma unroll
    for (int i = 0; i < TI; ++i) {
        v[i].x += __shfl_xor(v[i].x, 16, 64); v[i].y += __shfl_xor(v[i].y, 16, 64);
        v[i].z += __shfl_xor(v[i].z, 16, 64); v[i].w += __shfl_xor(v[i].w, 16, 64);
        v[i].x += __shfl_xor(v[i].x, 32, 64); v[i].y += __shfl_xor(v[i].y, 32, 64);
        v[i].z += __shfl_xor(v[i].z, 32, 64); v[i].w += __shfl_xor(v[i].w, 32, 64);
    }
    __syncthreads();                     // B4: a-reads done before union reuse
    if ((t & 63) < 16) {
#pragma unroll
        for (int i = 0; i < TI; ++i) sh.v[w][i][dq] = v[i];
    }
    __syncthreads();                                             // B5

    // final cross-wave reduce + coalesced store of partial o
    int i = t >> 6;       // 0..7
    int d = t & 63;       // 0..63
    const float* svf = (const float*)sh.v;
    float r = 0.f;
#pragma unroll
    for (int w2 = 0; w2 < 8; ++w2) r += svf[w2 * (TI * 64) + i * 64 + d];
    po[(size_t)bid * (TI * DD) + i * DD + d] = r;
}

// ---------------------------------------------------------------------------
// K3: merge the two j-halves: out = (o0*w0 + o1*w1) / (s0*w0 + s1*w1 + 1e-8)
// with w_h = exp(m_h - max(m0,m1)). Exactly the reference's ex/(sum+1e-8).
// ---------------------------------------------------------------------------
__global__ __launch_bounds__(256) void combine_kernel(
    const float* __restrict__ po, const float* __restrict__ pm,
    const float* __restrict__ ps, float* __restrict__ out)
{
    int gid    = blockIdx.x * 256 + threadIdx.x;   // 0 .. B*L*DD-1
    int d      = gid & 63;
    int row    = gid >> 6;          // 0..4095
    int rowblk = row >> 3;
    int i      = row & 7;
    float m0 = pm[rowblk * 16 + i],     m1 = pm[rowblk * 16 + 8 + i];
    float s0 = ps[rowblk * 16 + i],     s1 = ps[rowblk * 16 + 8 + i];
    float m  = fmaxf(m0, m1);
    float w0 = __expf(m0 - m), w1 = __expf(m1 - m);
    float s  = fmaf(s0, w0, s1 * w1) + 1e-8f;
    float o0 = po[(size_t)(rowblk * 2 + 0) * 512 + i * 64 + d];
    float o1 = po[(size_t)(rowblk * 2 + 1) * 512 + i * 64 + d];
    out[(size_t)row * DD + d] = fmaf(o0, w0, o1 * w1) * __builtin_amdgcn_rcpf(s);
}

// ---------------------------------------------------------------------------
extern "C" void kernel_launch(void* const* d_in, const int* in_sizes, int n_in,
                              void* d_out, int out_size, void* d_ws, size_t ws_size,
                              hipStream_t stream) {
    const float* inp = (const float*)d_in[0];
    const float* Wt  = (const float*)d_in[1];
    const float* Wx  = (const float*)d_in[2];
    const float* Wa  = (const float*)d_in[3];
    const float* bh  = (const float*)d_in[4];
    // d_in[5] = ba (cancels in softmax), d_in[6] = attention_width (dead code)
    float* out = (float*)d_out;

    float* Ekt = (float*)d_ws;                        // 512 KB
    float* po  = Ekt + (size_t)BB * LL * UU;          // 1024 * 512 floats = 2 MB
    float* pm  = po + (size_t)1024 * TI * DD;         // 16 KB
    float* ps  = pm + (size_t)512 * 16;               // 16 KB

    precompute_kernel<<<BB * LL / 8, 256, 0, stream>>>(inp, Wx, Ekt);
    attn_partial_kernel<<<2 * BB * LL / TI, NT, 0, stream>>>(
        Ekt, inp, Wt, Wa, bh, po, pm, ps);
    combine_kernel<<<BB * LL * DD / 256, 256, 0, stream>>>(po, pm, ps, out);
}